// Round 3
// baseline (20019.489 us; speedup 1.0000x reference)
//
#include <hip/hip_runtime.h>
#include <stdint.h>

#define TN 1024
#define CD 192
#define NB 8
#define NCLUST 196
#define NMERGE (TN - NCLUST)

typedef unsigned long long ull;

__device__ __forceinline__ uint32_t f2sort(float f) {
    uint32_t u = __float_as_uint(f);
    return u ^ ((u >> 31) ? 0xFFFFFFFFu : 0x80000000u);
}

__device__ __forceinline__ ull wave_min_ull(ull v) {
    #pragma unroll
    for (int off = 32; off > 0; off >>= 1) {
        ull o = (ull)__shfl_xor((long long)v, off, 64);
        if (o < v) v = o;
    }
    return v;
}

// ---------------- normalize rows: xn = x / ||x|| ----------------
__global__ void norm_kernel(const float* __restrict__ x, float* __restrict__ xn) {
    int row = blockIdx.x;          // 0..NB*TN-1
    int t = threadIdx.x;           // 256 threads, 192 active
    __shared__ float ssum[4];
    float v = 0.f;
    if (t < CD) v = x[(size_t)row * CD + t];
    float s = v * v;
    #pragma unroll
    for (int off = 32; off > 0; off >>= 1) s += __shfl_xor(s, off, 64);
    if ((t & 63) == 0) ssum[t >> 6] = s;
    __syncthreads();
    float tot = ssum[0] + ssum[1] + ssum[2] + ssum[3];
    float nrm = __fsqrt_rn(tot);
    if (t < CD) xn[(size_t)row * CD + t] = __fdiv_rn(v, nrm);
}

// ---------------- dist = 1 - xn @ xn^T, 64x64 tiles ----------------
#define KC 32
__global__ __launch_bounds__(256) void dist_kernel(const float* __restrict__ xn,
                                                   float* __restrict__ dout,
                                                   float* __restrict__ dwork) {
    int b = blockIdx.z;
    int bm = blockIdx.y, bn = blockIdx.x;
    const float* X = xn + (size_t)b * TN * CD;
    __shared__ float As[KC][68];
    __shared__ float Bs[KC][68];
    int tid = threadIdx.x;
    int tx = tid & 15, ty = tid >> 4;
    int lr = tid >> 2;   // 0..63 (row within tile)
    int lq = tid & 3;    // float4 slot
    float acc[4][4];
    #pragma unroll
    for (int r = 0; r < 4; ++r)
        #pragma unroll
        for (int c = 0; c < 4; ++c) acc[r][c] = 0.f;

    for (int kc = 0; kc < CD; kc += KC) {
        float4 a0 = *(const float4*)&X[(size_t)(bm * 64 + lr) * CD + kc + lq * 4];
        float4 a1 = *(const float4*)&X[(size_t)(bm * 64 + lr) * CD + kc + (lq + 4) * 4];
        float4 b0 = *(const float4*)&X[(size_t)(bn * 64 + lr) * CD + kc + lq * 4];
        float4 b1 = *(const float4*)&X[(size_t)(bn * 64 + lr) * CD + kc + (lq + 4) * 4];
        __syncthreads();
        As[lq * 4 + 0][lr] = a0.x; As[lq * 4 + 1][lr] = a0.y;
        As[lq * 4 + 2][lr] = a0.z; As[lq * 4 + 3][lr] = a0.w;
        As[lq * 4 + 16][lr] = a1.x; As[lq * 4 + 17][lr] = a1.y;
        As[lq * 4 + 18][lr] = a1.z; As[lq * 4 + 19][lr] = a1.w;
        Bs[lq * 4 + 0][lr] = b0.x; Bs[lq * 4 + 1][lr] = b0.y;
        Bs[lq * 4 + 2][lr] = b0.z; Bs[lq * 4 + 3][lr] = b0.w;
        Bs[lq * 4 + 16][lr] = b1.x; Bs[lq * 4 + 17][lr] = b1.y;
        Bs[lq * 4 + 18][lr] = b1.z; Bs[lq * 4 + 19][lr] = b1.w;
        __syncthreads();
        #pragma unroll
        for (int kk = 0; kk < KC; ++kk) {
            float4 av = *(const float4*)&As[kk][ty * 4];
            float4 bv = *(const float4*)&Bs[kk][tx * 4];
            acc[0][0] += av.x * bv.x; acc[0][1] += av.x * bv.y;
            acc[0][2] += av.x * bv.z; acc[0][3] += av.x * bv.w;
            acc[1][0] += av.y * bv.x; acc[1][1] += av.y * bv.y;
            acc[1][2] += av.y * bv.z; acc[1][3] += av.y * bv.w;
            acc[2][0] += av.z * bv.x; acc[2][1] += av.z * bv.y;
            acc[2][2] += av.z * bv.z; acc[2][3] += av.z * bv.w;
            acc[3][0] += av.w * bv.x; acc[3][1] += av.w * bv.y;
            acc[3][2] += av.w * bv.z; acc[3][3] += av.w * bv.w;
        }
    }
    size_t obase = (size_t)b * TN * TN;
    #pragma unroll
    for (int r = 0; r < 4; ++r) {
        int mrow = bm * 64 + ty * 4 + r;
        float4 o;
        o.x = 1.0f - acc[r][0]; o.y = 1.0f - acc[r][1];
        o.z = 1.0f - acc[r][2]; o.w = 1.0f - acc[r][3];
        size_t idx = obase + (size_t)mrow * TN + bn * 64 + tx * 4;
        *(float4*)&dout[idx] = o;
        *(float4*)&dwork[idx] = o;
    }
}

// ---------------- per-row argmin init ----------------
__global__ void rowmin_init_kernel(const float* __restrict__ D, ull* __restrict__ rowkey) {
    int gid = blockIdx.x;            // b*TN + r
    int bb = gid >> 10, r = gid & 1023;
    const float* Drow = D + (size_t)bb * TN * TN + (size_t)r * TN;
    int t = threadIdx.x;             // 256
    ull k = ~0ull;
    for (int s = t; s < TN; s += 256) {
        if (s != r) {
            ull key = ((ull)f2sort(Drow[s]) << 32) | (uint32_t)s;
            if (key < k) k = key;
        }
    }
    k = wave_min_ull(k);
    __shared__ ull part[4];
    if ((t & 63) == 0) part[t >> 6] = k;
    __syncthreads();
    if (t == 0) {
        ull m = part[0];
        #pragma unroll
        for (int w = 1; w < 4; ++w) if (part[w] < m) m = part[w];
        rowkey[gid] = m;
    }
}

// ---------------- sequential agglomerative clustering: ONE WAVE per batch ----------------
// Wave-synchronous: no barriers in the merge loop. Full symmetric freshness is
// maintained (row + column write per merge); column stores issued last so their
// drain overlaps the next iteration's LDS-only argmin phase. All reductions via
// single-instruction LDS atomicMin on a u64 cell.
__global__ __launch_bounds__(64) void cluster_kernel(float* __restrict__ D,
                                                     const ull* __restrict__ rowkey_init,
                                                     float* __restrict__ out_labels) {
    int b = blockIdx.x;
    float* Db = D + (size_t)b * TN * TN;
    int lane = threadIdx.x;          // 0..63

    __shared__ ull rowkey[TN];       // (sortable val << 32) | argmin col; ~0 = dead
    __shared__ float newrow[TN];     // merged row of current iteration
    __shared__ float sizes_l[TN];
    __shared__ int parent[TN];       // parent[j] = i when j merged into i
    __shared__ uint32_t aw[TN / 32]; // active bitmask
    __shared__ int list_l[TN];       // rows needing full NN recompute
    __shared__ ull cellA;
    __shared__ ull cellC;
    __shared__ int nrec;
    __shared__ int woff_l[32];

    #pragma unroll
    for (int t = 0; t < 16; ++t) {
        int k = lane + 64 * t;
        rowkey[k] = rowkey_init[b * TN + k];
        sizes_l[k] = 1.0f;
        parent[k] = k;
    }
    if (lane < 32) aw[lane] = 0xFFFFFFFFu;
    if (lane == 0) { cellA = ~0ull; cellC = ~0ull; nrec = 0; }
    __syncthreads();

    for (int m = 0; m < NMERGE; ++m) {
        // ---- Phase A: global argmin over (val, row) — register scan + LDS atomic ----
        ull rk[16];
        ull best = ~0ull;
        #pragma unroll
        for (int t = 0; t < 16; ++t) {
            int k = lane + 64 * t;
            rk[t] = rowkey[k];
            ull cand = (rk[t] & 0xFFFFFFFF00000000ull) | (uint32_t)k;
            if (cand < best) best = cand;
        }
        atomicMin(&cellA, best);
        __builtin_amdgcn_wave_barrier();
        ull g = cellA;                       // all lanes: broadcast read (after atomic, in-order DS)
        int i = (int)(uint32_t)g;
        int j = (int)(uint32_t)rowkey[i];
        float ni = sizes_l[i], nj = sizes_l[j];
        __builtin_amdgcn_wave_barrier();
        if (lane == 0) {
            cellA = ~0ull;
            sizes_l[i] = __fadd_rn(ni, nj);
            rowkey[j] = ~0ull;               // poison dead row
            parent[j] = i;
            aw[j >> 5] &= ~(1u << (j & 31));
            nrec = 0;
        }
        __builtin_amdgcn_wave_barrier();

        // ---- Phase B: merged row (coalesced loads of rows i and j) ----
        float ssum = __fadd_rn(ni, nj);
        const float* Ri = Db + (size_t)i * TN;
        const float* Rj = Db + (size_t)j * TN;
        float4 nr4[4];
        #pragma unroll
        for (int q = 0; q < 4; ++q) {
            int k0 = lane * 4 + q * 256;
            float4 a = *(const float4*)(Ri + k0);
            float4 c = *(const float4*)(Rj + k0);
            float4 r;
            r.x = __fdiv_rn(__fadd_rn(__fmul_rn(ni, a.x), __fmul_rn(nj, c.x)), ssum);
            r.y = __fdiv_rn(__fadd_rn(__fmul_rn(ni, a.y), __fmul_rn(nj, c.y)), ssum);
            r.z = __fdiv_rn(__fadd_rn(__fmul_rn(ni, a.z), __fmul_rn(nj, c.z)), ssum);
            r.w = __fdiv_rn(__fadd_rn(__fmul_rn(ni, a.w), __fmul_rn(nj, c.w)), ssum);
            *(float4*)(Db + (size_t)i * TN + k0) = r;   // coalesced row-i write
            *(float4*)(&newrow[k0]) = r;
            nr4[q] = r;
        }
        __builtin_amdgcn_wave_barrier();

        // ---- Phase D: incremental rowkey maintenance ----
        #pragma unroll
        for (int t = 0; t < 16; ++t) {
            int k = lane + 64 * t;
            ull K = rk[t];
            if (k == i || k == j || K == ~0ull) continue;
            uint32_t c = (uint32_t)K;
            uint32_t vhi = (uint32_t)(K >> 32);
            uint32_t nrs = f2sort(newrow[k]);
            if (c == (uint32_t)i || c == (uint32_t)j) {
                // old NN invalidated; if merged value doesn't rise past it, (nr,i) is the new min
                if (nrs <= vhi) rowkey[k] = ((ull)nrs << 32) | (uint32_t)i;
                else { int idx = atomicAdd(&nrec, 1); list_l[idx] = k; }
            } else {
                ull cand = ((ull)nrs << 32) | (uint32_t)i;
                if (cand < K) rowkey[k] = cand;
            }
        }
        __builtin_amdgcn_wave_barrier();

        // ---- Phase C0: recompute row i's NN from LDS newrow ----
        {
            ull bst = ~0ull;
            #pragma unroll
            for (int t = 0; t < 16; ++t) {
                int s2 = lane + 64 * t;
                bool ok = (((aw[s2 >> 5] >> (s2 & 31)) & 1u) != 0u) && (s2 != i);
                if (ok) {
                    ull key = ((ull)f2sort(newrow[s2]) << 32) | (uint32_t)s2;
                    if (key < bst) bst = key;
                }
            }
            atomicMin(&cellC, bst);
            __builtin_amdgcn_wave_barrier();
            if (lane == 0) { rowkey[i] = cellC; cellC = ~0ull; }
            __builtin_amdgcn_wave_barrier();
        }

        // ---- Phase C: full rescans for invalidated rows (coalesced, col-i patched from LDS) ----
        int ncr = nrec;
        for (int z = 0; z < ncr; ++z) {
            int r = list_l[z];
            const float* Rr = Db + (size_t)r * TN;
            float pv = newrow[r];
            ull bst = ~0ull;
            #pragma unroll
            for (int q = 0; q < 4; ++q) {
                int s0 = lane * 4 + q * 256;
                float4 v = *(const float4*)(Rr + s0);
                uint32_t bits = (aw[s0 >> 5] >> (s0 & 31)) & 0xFu;
                float e0 = (s0 + 0 == i) ? pv : v.x;
                float e1 = (s0 + 1 == i) ? pv : v.y;
                float e2 = (s0 + 2 == i) ? pv : v.z;
                float e3 = (s0 + 3 == i) ? pv : v.w;
                if ((bits & 1u) && (s0 + 0) != r) { ull key = ((ull)f2sort(e0) << 32) | (uint32_t)(s0 + 0); if (key < bst) bst = key; }
                if ((bits & 2u) && (s0 + 1) != r) { ull key = ((ull)f2sort(e1) << 32) | (uint32_t)(s0 + 1); if (key < bst) bst = key; }
                if ((bits & 4u) && (s0 + 2) != r) { ull key = ((ull)f2sort(e2) << 32) | (uint32_t)(s0 + 2); if (key < bst) bst = key; }
                if ((bits & 8u) && (s0 + 3) != r) { ull key = ((ull)f2sort(e3) << 32) | (uint32_t)(s0 + 3); if (key < bst) bst = key; }
            }
            atomicMin(&cellC, bst);
            __builtin_amdgcn_wave_barrier();
            if (lane == 0) { rowkey[r] = cellC; cellC = ~0ull; }
            __builtin_amdgcn_wave_barrier();
        }
        __builtin_amdgcn_wave_barrier();

        // ---- column-i stores LAST: drain overlaps next iteration's LDS-only Phase A ----
        #pragma unroll
        for (int q = 0; q < 4; ++q) {
            int k0 = lane * 4 + q * 256;
            Db[(size_t)(k0 + 0) * TN + i] = nr4[q].x;
            Db[(size_t)(k0 + 1) * TN + i] = nr4[q].y;
            Db[(size_t)(k0 + 2) * TN + i] = nr4[q].z;
            Db[(size_t)(k0 + 3) * TN + i] = nr4[q].w;
        }
    }

    // ---- epilogue: labels = rank of cluster root among active reps ----
    __syncthreads();
    if (lane == 0) {
        int run = 0;
        for (int w = 0; w < 32; ++w) { woff_l[w] = run; run += __popc(aw[w]); }
    }
    __syncthreads();
    #pragma unroll
    for (int t = 0; t < 16; ++t) {
        int k = lane + 64 * t;
        int p = k;
        while (((aw[p >> 5] >> (p & 31)) & 1u) == 0u) p = parent[p];
        int rank = woff_l[p >> 5] + __popc(aw[p >> 5] & ((1u << (p & 31)) - 1u));
        out_labels[(size_t)b * TN + k] = (float)rank;
    }
}

extern "C" void kernel_launch(void* const* d_in, const int* in_sizes, int n_in,
                              void* d_out, int out_size, void* d_ws, size_t ws_size,
                              hipStream_t stream) {
    const float* x = (const float*)d_in[0];
    float* out = (float*)d_out;

    float* xn    = (float*)d_ws;                          // NB*TN*CD floats (6.3 MB)
    float* Dwork = xn + (size_t)NB * TN * CD;             // NB*TN*TN floats (33.6 MB)
    ull*   rowkey = (ull*)(Dwork + (size_t)NB * TN * TN); // NB*TN u64 (64 KB)

    float* dist_out   = out;
    float* labels_out = out + (size_t)NB * TN * TN;

    norm_kernel<<<NB * TN, 256, 0, stream>>>(x, xn);
    dim3 g2(16, 16, NB);
    dist_kernel<<<g2, 256, 0, stream>>>(xn, dist_out, Dwork);
    rowmin_init_kernel<<<NB * TN, 256, 0, stream>>>(Dwork, rowkey);
    cluster_kernel<<<NB, 64, 0, stream>>>(Dwork, rowkey, labels_out);
}

// Round 4
// 6530.228 us; speedup vs baseline: 3.0657x; 3.0657x over previous
//
#include <hip/hip_runtime.h>
#include <stdint.h>

#define TN 1024
#define CD 192
#define NB 8
#define NCLUST 196
#define NMERGE (TN - NCLUST)
#define FW 16            // journal slots = flush window

typedef unsigned long long ull;

__device__ __forceinline__ uint32_t f2sort(float f) {
    uint32_t u = __float_as_uint(f);
    return u ^ ((u >> 31) ? 0xFFFFFFFFu : 0x80000000u);
}

__device__ __forceinline__ ull wave_min_ull(ull v) {
    #pragma unroll
    for (int off = 32; off > 0; off >>= 1) {
        ull o = (ull)__shfl_xor((long long)v, off, 64);
        if (o < v) v = o;
    }
    return v;
}

// ---------------- normalize rows: xn = x / ||x|| ----------------
__global__ void norm_kernel(const float* __restrict__ x, float* __restrict__ xn) {
    int row = blockIdx.x;
    int t = threadIdx.x;
    __shared__ float ssum[4];
    float v = 0.f;
    if (t < CD) v = x[(size_t)row * CD + t];
    float s = v * v;
    #pragma unroll
    for (int off = 32; off > 0; off >>= 1) s += __shfl_xor(s, off, 64);
    if ((t & 63) == 0) ssum[t >> 6] = s;
    __syncthreads();
    float tot = ssum[0] + ssum[1] + ssum[2] + ssum[3];
    float nrm = __fsqrt_rn(tot);
    if (t < CD) xn[(size_t)row * CD + t] = __fdiv_rn(v, nrm);
}

// ---------------- dist = 1 - xn @ xn^T, 64x64 tiles ----------------
#define KC 32
__global__ __launch_bounds__(256) void dist_kernel(const float* __restrict__ xn,
                                                   float* __restrict__ dout,
                                                   float* __restrict__ dwork) {
    int b = blockIdx.z;
    int bm = blockIdx.y, bn = blockIdx.x;
    const float* X = xn + (size_t)b * TN * CD;
    __shared__ float As[KC][68];
    __shared__ float Bs[KC][68];
    int tid = threadIdx.x;
    int tx = tid & 15, ty = tid >> 4;
    int lr = tid >> 2;
    int lq = tid & 3;
    float acc[4][4];
    #pragma unroll
    for (int r = 0; r < 4; ++r)
        #pragma unroll
        for (int c = 0; c < 4; ++c) acc[r][c] = 0.f;

    for (int kc = 0; kc < CD; kc += KC) {
        float4 a0 = *(const float4*)&X[(size_t)(bm * 64 + lr) * CD + kc + lq * 4];
        float4 a1 = *(const float4*)&X[(size_t)(bm * 64 + lr) * CD + kc + (lq + 4) * 4];
        float4 b0 = *(const float4*)&X[(size_t)(bn * 64 + lr) * CD + kc + lq * 4];
        float4 b1 = *(const float4*)&X[(size_t)(bn * 64 + lr) * CD + kc + (lq + 4) * 4];
        __syncthreads();
        As[lq * 4 + 0][lr] = a0.x; As[lq * 4 + 1][lr] = a0.y;
        As[lq * 4 + 2][lr] = a0.z; As[lq * 4 + 3][lr] = a0.w;
        As[lq * 4 + 16][lr] = a1.x; As[lq * 4 + 17][lr] = a1.y;
        As[lq * 4 + 18][lr] = a1.z; As[lq * 4 + 19][lr] = a1.w;
        Bs[lq * 4 + 0][lr] = b0.x; Bs[lq * 4 + 1][lr] = b0.y;
        Bs[lq * 4 + 2][lr] = b0.z; Bs[lq * 4 + 3][lr] = b0.w;
        Bs[lq * 4 + 16][lr] = b1.x; Bs[lq * 4 + 17][lr] = b1.y;
        Bs[lq * 4 + 18][lr] = b1.z; Bs[lq * 4 + 19][lr] = b1.w;
        __syncthreads();
        #pragma unroll
        for (int kk = 0; kk < KC; ++kk) {
            float4 av = *(const float4*)&As[kk][ty * 4];
            float4 bv = *(const float4*)&Bs[kk][tx * 4];
            acc[0][0] += av.x * bv.x; acc[0][1] += av.x * bv.y;
            acc[0][2] += av.x * bv.z; acc[0][3] += av.x * bv.w;
            acc[1][0] += av.y * bv.x; acc[1][1] += av.y * bv.y;
            acc[1][2] += av.y * bv.z; acc[1][3] += av.y * bv.w;
            acc[2][0] += av.z * bv.x; acc[2][1] += av.z * bv.y;
            acc[2][2] += av.z * bv.z; acc[2][3] += av.z * bv.w;
            acc[3][0] += av.w * bv.x; acc[3][1] += av.w * bv.y;
            acc[3][2] += av.w * bv.z; acc[3][3] += av.w * bv.w;
        }
    }
    size_t obase = (size_t)b * TN * TN;
    #pragma unroll
    for (int r = 0; r < 4; ++r) {
        int mrow = bm * 64 + ty * 4 + r;
        float4 o;
        o.x = 1.0f - acc[r][0]; o.y = 1.0f - acc[r][1];
        o.z = 1.0f - acc[r][2]; o.w = 1.0f - acc[r][3];
        size_t idx = obase + (size_t)mrow * TN + bn * 64 + tx * 4;
        *(float4*)&dout[idx] = o;
        *(float4*)&dwork[idx] = o;
    }
}

// ---------------- per-row argmin init ----------------
__global__ void rowmin_init_kernel(const float* __restrict__ D, ull* __restrict__ rowkey) {
    int gid = blockIdx.x;
    int bb = gid >> 10, r = gid & 1023;
    const float* Drow = D + (size_t)bb * TN * TN + (size_t)r * TN;
    int t = threadIdx.x;
    ull k = ~0ull;
    for (int s = t; s < TN; s += 256) {
        if (s != r) {
            ull key = ((ull)f2sort(Drow[s]) << 32) | (uint32_t)s;
            if (key < k) k = key;
        }
    }
    k = wave_min_ull(k);
    __shared__ ull part[4];
    if ((t & 63) == 0) part[t >> 6] = k;
    __syncthreads();
    if (t == 0) {
        ull m = part[0];
        #pragma unroll
        for (int w = 1; w < 4; ++w) if (part[w] < m) m = part[w];
        rowkey[gid] = m;
    }
}

// ---------------- agglomerative clustering: 16 waves/batch, LDS journal + flush ----------------
// Global D: row-only coalesced writes. Freshness of pair (r,s) = row written at
// max(ts[r],ts[s]); newer-than-row columns are ALWAYS in the LDS journal because a
// flush every FW merges rewrites all active rows fresh. Zero scattered global ops.
__global__ __launch_bounds__(1024) void cluster_kernel(float* __restrict__ D,
                                                       const ull* __restrict__ rowkey_init,
                                                       float* __restrict__ out_labels) {
    int b = blockIdx.x;
    float* Db = D + (size_t)b * TN * TN;
    int k = threadIdx.x;
    int lane = k & 63, wave = k >> 6;

    __shared__ float Jl[FW * TN];      // 64 KB journal of last FW merged rows
    __shared__ ull rowkey[TN];         // (sortable val << 32) | argmin col; ~0 = dead
    __shared__ float sizes_l[TN];
    __shared__ int ts_l[TN];           // merge index when row last materialized
    __shared__ int slot_l[TN];         // journal slot of that materialization
    __shared__ int parent_l[TN];
    __shared__ uint32_t aw[TN / 32];
    __shared__ int list_l[TN];
    __shared__ int nrec;
    __shared__ ull wpart[16];
    __shared__ int bc_i, bc_j, bc_tsi, bc_tsj;
    __shared__ float bc_ni, bc_nj;
    __shared__ int prefix_w[16], woff[16];

    rowkey[k] = rowkey_init[b * TN + k];
    sizes_l[k] = 1.0f;
    ts_l[k] = -1;
    slot_l[k] = 0;
    parent_l[k] = k;
    if (k < TN / 32) aw[k] = 0xFFFFFFFFu;
    if (k == 0) nrec = 0;
    __syncthreads();

    for (int m = 0; m < NMERGE; ++m) {
        int slot = m & (FW - 1);

        // ---- Phase A: global argmin (val, row) ----
        ull K0 = rowkey[k];
        ull cand = (K0 & 0xFFFFFFFF00000000ull) | (uint32_t)k;
        ull wmin = wave_min_ull(cand);
        if (lane == 0) wpart[wave] = wmin;
        __syncthreads();                                   // bar1
        if (wave == 0) {
            ull v = (lane < 16) ? wpart[lane] : ~0ull;
            v = wave_min_ull(v);
            if (lane == 0) {
                int i = (int)(uint32_t)v;
                int j = (int)(uint32_t)rowkey[i];
                bc_i = i; bc_j = j;
                bc_tsi = ts_l[i]; bc_tsj = ts_l[j];
                float ni = sizes_l[i], nj = sizes_l[j];
                bc_ni = ni; bc_nj = nj;
                sizes_l[i] = __fadd_rn(ni, nj);
                rowkey[j] = ~0ull;                         // poison dead row
                parent_l[j] = i;
                aw[j >> 5] &= ~(1u << (j & 31));
                ts_l[i] = m;
                slot_l[i] = slot;
                nrec = 0;
            }
        }
        __syncthreads();                                   // bar2
        int i = bc_i, j = bc_j;
        int tsi = bc_tsi, tsj = bc_tsj;
        float ni = bc_ni, nj = bc_nj;
        float ssum = __fadd_rn(ni, nj);

        // ---- Phase B: fresh rows i,j (coalesced + journal patches), merged row ----
        int tsk = ts_l[k];
        int slk = slot_l[k];
        float di = Db[(size_t)i * TN + k];
        float dj = Db[(size_t)j * TN + k];
        if (tsk > tsi) di = Jl[slk * TN + i];
        if (tsk > tsj) dj = Jl[slk * TN + j];
        float nr = __fdiv_rn(__fadd_rn(__fmul_rn(ni, di), __fmul_rn(nj, dj)), ssum);
        Db[(size_t)i * TN + k] = nr;                       // coalesced row write
        Jl[slot * TN + k] = nr;                            // journal write

        // ---- Phase D: incremental rowkey maintenance ----
        if (k != i && k != j && K0 != ~0ull) {
            uint32_t c = (uint32_t)K0;
            uint32_t vhi = (uint32_t)(K0 >> 32);
            uint32_t nrs = f2sort(nr);
            if (c == (uint32_t)i || c == (uint32_t)j) {
                if (nrs <= vhi) rowkey[k] = ((ull)nrs << 32) | (uint32_t)i;
                else { int idx = atomicAdd(&nrec, 1); list_l[idx] = k; }
            } else {
                ull cc = ((ull)nrs << 32) | (uint32_t)i;
                if (cc < K0) rowkey[k] = cc;
            }
        }
        __syncthreads();                                   // bar3
        int ncr = nrec;

        // ---- Phase C: wave0 recomputes row i's NN from journal (LDS); waves 1..15
        //      rescan invalidated rows in parallel (coalesced + journal patches) ----
        if (wave == 0) {
            ull bst = ~0ull;
            #pragma unroll
            for (int t = 0; t < 16; ++t) {
                int s = lane + 64 * t;
                if (((aw[s >> 5] >> (s & 31)) & 1u) && s != i) {
                    ull key = ((ull)f2sort(Jl[slot * TN + s]) << 32) | (uint32_t)s;
                    if (key < bst) bst = key;
                }
            }
            bst = wave_min_ull(bst);
            if (lane == 0) rowkey[i] = bst;
        } else {
            for (int z = wave - 1; z < ncr; z += 15) {
                int r = list_l[z];
                int tsr = ts_l[r];
                const float* Rr = Db + (size_t)r * TN;
                ull bst = ~0ull;
                #pragma unroll
                for (int q = 0; q < 4; ++q) {
                    int s0 = (lane << 2) + (q << 8);
                    float4 v = *(const float4*)(Rr + s0);
                    uint32_t bits = (aw[s0 >> 5] >> (s0 & 31)) & 0xFu;
                    #pragma unroll
                    for (int e = 0; e < 4; ++e) {
                        int s = s0 + e;
                        if (!((bits >> e) & 1u) || s == r) continue;
                        float val = (&v.x)[e];
                        if (ts_l[s] > tsr) val = Jl[slot_l[s] * TN + r];
                        ull key = ((ull)f2sort(val) << 32) | (uint32_t)s;
                        if (key < bst) bst = key;
                    }
                }
                bst = wave_min_ull(bst);
                if (lane == 0) rowkey[r] = bst;
            }
        }
        __syncthreads();                                   // bar4

        // ---- flush: journal full -> rewrite all active rows fresh (coalesced) ----
        if (slot == FW - 1) {
            for (int r = wave; r < TN; r += 16) {
                if (!((aw[r >> 5] >> (r & 31)) & 1u)) continue;
                int tsr = ts_l[r];
                if (tsr == m) continue;                    // just-merged row already fresh
                float* Rr = Db + (size_t)r * TN;
                #pragma unroll
                for (int q = 0; q < 4; ++q) {
                    int s0 = (lane << 2) + (q << 8);
                    float4 v = *(float4*)(Rr + s0);
                    #pragma unroll
                    for (int e = 0; e < 4; ++e) {
                        int s = s0 + e;
                        if (ts_l[s] > tsr) (&v.x)[e] = Jl[slot_l[s] * TN + r];
                    }
                    *(float4*)(Rr + s0) = v;
                }
            }
            __syncthreads();
            ts_l[k] = m;                                   // all rows now epoch-fresh
            __syncthreads();
        }
    }

    // ---- epilogue: labels = rank of cluster root among active reps ----
    int a = (aw[k >> 5] >> (k & 31)) & 1;
    ull mask = __ballot(a);
    int lanepre = __popcll(mask & (((ull)1 << lane) - 1ull));
    if (lane == 0) prefix_w[wave] = __popcll(mask);
    __syncthreads();
    if (k == 0) {
        int run = 0;
        for (int w2 = 0; w2 < 16; ++w2) { woff[w2] = run; run += prefix_w[w2]; }
    }
    __syncthreads();
    list_l[k] = woff[wave] + lanepre;   // rank of k among active (valid when k active)
    __syncthreads();
    int p = k;
    while (!((aw[p >> 5] >> (p & 31)) & 1u)) p = parent_l[p];
    out_labels[(size_t)b * TN + k] = (float)list_l[p];
}

extern "C" void kernel_launch(void* const* d_in, const int* in_sizes, int n_in,
                              void* d_out, int out_size, void* d_ws, size_t ws_size,
                              hipStream_t stream) {
    const float* x = (const float*)d_in[0];
    float* out = (float*)d_out;

    float* xn    = (float*)d_ws;                          // NB*TN*CD floats
    float* Dwork = xn + (size_t)NB * TN * CD;             // NB*TN*TN floats
    ull*   rowkey = (ull*)(Dwork + (size_t)NB * TN * TN); // NB*TN u64

    float* dist_out   = out;
    float* labels_out = out + (size_t)NB * TN * TN;

    norm_kernel<<<NB * TN, 256, 0, stream>>>(x, xn);
    dim3 g2(16, 16, NB);
    dist_kernel<<<g2, 256, 0, stream>>>(xn, dist_out, Dwork);
    rowmin_init_kernel<<<NB * TN, 256, 0, stream>>>(Dwork, rowkey);
    cluster_kernel<<<NB, 1024, 0, stream>>>(Dwork, rowkey, labels_out);
}

// Round 5
// 4407.090 us; speedup vs baseline: 4.5426x; 1.4818x over previous
//
#include <hip/hip_runtime.h>
#include <stdint.h>

#define TN 1024
#define CD 192
#define NB 8
#define NCLUST 196
#define NMERGE (TN - NCLUST)

typedef unsigned long long ull;

// Workgroup barrier WITHOUT global-memory drain: LDS ops made visible
// (lgkmcnt(0)), global stores stay in flight. "memory" clobber pins ordering.
#define LBAR() asm volatile("s_waitcnt lgkmcnt(0)\n\ts_barrier" ::: "memory")
// Full fence barrier: drains all global stores too.
#define FBAR() asm volatile("s_waitcnt vmcnt(0) lgkmcnt(0)\n\ts_barrier" ::: "memory")

__device__ __forceinline__ uint32_t f2sort(float f) {
    uint32_t u = __float_as_uint(f);
    return u ^ ((u >> 31) ? 0xFFFFFFFFu : 0x80000000u);
}

__device__ __forceinline__ ull wave_min_ull(ull v) {
    #pragma unroll
    for (int off = 32; off > 0; off >>= 1) {
        ull o = (ull)__shfl_xor((long long)v, off, 64);
        if (o < v) v = o;
    }
    return v;
}

// ---------------- normalize rows: xn = x / ||x|| ----------------
__global__ void norm_kernel(const float* __restrict__ x, float* __restrict__ xn) {
    int row = blockIdx.x;
    int t = threadIdx.x;
    __shared__ float ssum[4];
    float v = 0.f;
    if (t < CD) v = x[(size_t)row * CD + t];
    float s = v * v;
    #pragma unroll
    for (int off = 32; off > 0; off >>= 1) s += __shfl_xor(s, off, 64);
    if ((t & 63) == 0) ssum[t >> 6] = s;
    __syncthreads();
    float tot = ssum[0] + ssum[1] + ssum[2] + ssum[3];
    float nrm = __fsqrt_rn(tot);
    if (t < CD) xn[(size_t)row * CD + t] = __fdiv_rn(v, nrm);
}

// ---------------- dist = 1 - xn @ xn^T, 64x64 tiles ----------------
#define KC 32
__global__ __launch_bounds__(256) void dist_kernel(const float* __restrict__ xn,
                                                   float* __restrict__ dout,
                                                   float* __restrict__ dwork) {
    int b = blockIdx.z;
    int bm = blockIdx.y, bn = blockIdx.x;
    const float* X = xn + (size_t)b * TN * CD;
    __shared__ float As[KC][68];
    __shared__ float Bs[KC][68];
    int tid = threadIdx.x;
    int tx = tid & 15, ty = tid >> 4;
    int lr = tid >> 2;
    int lq = tid & 3;
    float acc[4][4];
    #pragma unroll
    for (int r = 0; r < 4; ++r)
        #pragma unroll
        for (int c = 0; c < 4; ++c) acc[r][c] = 0.f;

    for (int kc = 0; kc < CD; kc += KC) {
        float4 a0 = *(const float4*)&X[(size_t)(bm * 64 + lr) * CD + kc + lq * 4];
        float4 a1 = *(const float4*)&X[(size_t)(bm * 64 + lr) * CD + kc + (lq + 4) * 4];
        float4 b0 = *(const float4*)&X[(size_t)(bn * 64 + lr) * CD + kc + lq * 4];
        float4 b1 = *(const float4*)&X[(size_t)(bn * 64 + lr) * CD + kc + (lq + 4) * 4];
        __syncthreads();
        As[lq * 4 + 0][lr] = a0.x; As[lq * 4 + 1][lr] = a0.y;
        As[lq * 4 + 2][lr] = a0.z; As[lq * 4 + 3][lr] = a0.w;
        As[lq * 4 + 16][lr] = a1.x; As[lq * 4 + 17][lr] = a1.y;
        As[lq * 4 + 18][lr] = a1.z; As[lq * 4 + 19][lr] = a1.w;
        Bs[lq * 4 + 0][lr] = b0.x; Bs[lq * 4 + 1][lr] = b0.y;
        Bs[lq * 4 + 2][lr] = b0.z; Bs[lq * 4 + 3][lr] = b0.w;
        Bs[lq * 4 + 16][lr] = b1.x; Bs[lq * 4 + 17][lr] = b1.y;
        Bs[lq * 4 + 18][lr] = b1.z; Bs[lq * 4 + 19][lr] = b1.w;
        __syncthreads();
        #pragma unroll
        for (int kk = 0; kk < KC; ++kk) {
            float4 av = *(const float4*)&As[kk][ty * 4];
            float4 bv = *(const float4*)&Bs[kk][tx * 4];
            acc[0][0] += av.x * bv.x; acc[0][1] += av.x * bv.y;
            acc[0][2] += av.x * bv.z; acc[0][3] += av.x * bv.w;
            acc[1][0] += av.y * bv.x; acc[1][1] += av.y * bv.y;
            acc[1][2] += av.y * bv.z; acc[1][3] += av.y * bv.w;
            acc[2][0] += av.z * bv.x; acc[2][1] += av.z * bv.y;
            acc[2][2] += av.z * bv.z; acc[2][3] += av.z * bv.w;
            acc[3][0] += av.w * bv.x; acc[3][1] += av.w * bv.y;
            acc[3][2] += av.w * bv.z; acc[3][3] += av.w * bv.w;
        }
    }
    size_t obase = (size_t)b * TN * TN;
    #pragma unroll
    for (int r = 0; r < 4; ++r) {
        int mrow = bm * 64 + ty * 4 + r;
        float4 o;
        o.x = 1.0f - acc[r][0]; o.y = 1.0f - acc[r][1];
        o.z = 1.0f - acc[r][2]; o.w = 1.0f - acc[r][3];
        size_t idx = obase + (size_t)mrow * TN + bn * 64 + tx * 4;
        *(float4*)&dout[idx] = o;
        *(float4*)&dwork[idx] = o;
    }
}

// ---------------- per-row argmin init ----------------
__global__ void rowmin_init_kernel(const float* __restrict__ D, ull* __restrict__ rowkey) {
    int gid = blockIdx.x;
    int bb = gid >> 10, r = gid & 1023;
    const float* Drow = D + (size_t)bb * TN * TN + (size_t)r * TN;
    int t = threadIdx.x;
    ull k = ~0ull;
    for (int s = t; s < TN; s += 256) {
        if (s != r) {
            ull key = ((ull)f2sort(Drow[s]) << 32) | (uint32_t)s;
            if (key < k) k = key;
        }
    }
    k = wave_min_ull(k);
    __shared__ ull part[4];
    if ((t & 63) == 0) part[t >> 6] = k;
    __syncthreads();
    if (t == 0) {
        ull m = part[0];
        #pragma unroll
        for (int w = 1; w < 4; ++w) if (part[w] < m) m = part[w];
        rowkey[gid] = m;
    }
}

// ---------------- agglomerative clustering: 16 waves/batch ----------------
// Symmetric D maintained by coalesced row write + fire-and-forget scattered col
// write per merge. Barriers do NOT drain global stores; a 16-slot LDS journal
// bridges unlanded data: element (r,s) is read from the journal slot of
// max(ts[r],ts[s]) while that merge is < 16 iters old, else from global (landed,
// because a full vmcnt(0) fence runs every 8 iters). Store-store races between
// merges in the same un-drained window are repaired by a fix-up pass between
// two fences.
__global__ __launch_bounds__(1024) void cluster_kernel(float* __restrict__ D,
                                                       const ull* __restrict__ rowkey_init,
                                                       float* __restrict__ out_labels) {
    int b = blockIdx.x;
    float* Db = D + (size_t)b * TN * TN;
    int k = threadIdx.x;
    int lane = k & 63, wave = k >> 6;

    __shared__ float Jl[16 * TN];        // 64 KB journal ring of last 16 merged rows
    __shared__ ull rowkey[TN];           // (sortable val << 32) | argmin col; ~0 = dead
    __shared__ float sizes_l[TN];
    __shared__ int ts_l[TN] __attribute__((aligned(16)));
    __shared__ int parent_l[TN];
    __shared__ uint32_t aw[TN / 32];
    __shared__ int list_l[TN];
    __shared__ int nrecb[2];
    __shared__ ull wpart[16];
    __shared__ int wtarg[8];             // merge targets of current fence window
    __shared__ int prefix_w[16], woff[16];

    rowkey[k] = rowkey_init[b * TN + k];
    sizes_l[k] = 1.0f;
    ts_l[k] = -1000000;
    parent_l[k] = k;
    if (k < TN / 32) aw[k] = 0xFFFFFFFFu;
    if (k < 2) nrecb[k] = 0;
    __syncthreads();

    for (int m = 0; m < NMERGE; ++m) {
        int m16 = m - 16;

        // ---- Phase A: global argmin (val, row) ----
        ull K0 = rowkey[k];
        ull cand = (K0 & 0xFFFFFFFF00000000ull) | (uint32_t)k;
        ull wmin = wave_min_ull(cand);
        if (lane == 0) wpart[wave] = wmin;
        LBAR();                                            // bar1
        ull v16 = (lane < 16) ? wpart[lane] : ~0ull;
        ull gmin = wave_min_ull(v16);                      // all waves redundantly
        int i = (int)(uint32_t)gmin;
        int j = (int)(uint32_t)rowkey[i];
        float ni = sizes_l[i], nj = sizes_l[j];
        int tsi = ts_l[i], tsj = ts_l[j];
        LBAR();                                            // bar2
        if (k == 0) {
            sizes_l[i] = __fadd_rn(ni, nj);
            ts_l[i] = m;
            rowkey[j] = ~0ull;
            parent_l[j] = i;
            aw[j >> 5] &= ~(1u << (j & 31));
            wtarg[m & 7] = i;
            nrecb[(m & 1) ^ 1] = 0;
        }

        // ---- Phase B: fresh rows i,j (global + journal bridge), merged row ----
        int tsk = ts_l[k];
        float gvi = Db[(size_t)i * TN + k];
        float gvj = Db[(size_t)j * TN + k];
        float di, dj;
        if (tsk > tsi) di = (tsk > m16) ? Jl[(tsk & 15) * TN + i] : gvi;
        else           di = (tsi > m16) ? Jl[(tsi & 15) * TN + k] : gvi;
        if (tsk > tsj) dj = (tsk > m16) ? Jl[(tsk & 15) * TN + j] : gvj;
        else           dj = (tsj > m16) ? Jl[(tsj & 15) * TN + k] : gvj;
        float ssum = __fadd_rn(ni, nj);
        float nr = __fdiv_rn(__fadd_rn(__fmul_rn(ni, di), __fmul_rn(nj, dj)), ssum);
        Jl[(m & 15) * TN + k] = nr;                        // journal (LDS)
        Db[(size_t)i * TN + k] = nr;                       // coalesced row write
        Db[(size_t)k * TN + i] = nr;                       // scattered col write, fire&forget

        // ---- Phase D: incremental rowkey maintenance ----
        if (k != i && k != j && K0 != ~0ull) {
            uint32_t c = (uint32_t)K0;
            uint32_t vhi = (uint32_t)(K0 >> 32);
            uint32_t nrs = f2sort(nr);
            if (c == (uint32_t)i || c == (uint32_t)j) {
                if (nrs <= vhi) rowkey[k] = ((ull)nrs << 32) | (uint32_t)i;
                else { int idx = atomicAdd(&nrecb[m & 1], 1); list_l[idx] = k; }
            } else {
                ull cc = ((ull)nrs << 32) | (uint32_t)i;
                if (cc < K0) rowkey[k] = cc;
            }
        }
        LBAR();                                            // bar3
        int ncr = nrecb[m & 1];

        // ---- Phase C: wave0 -> row i NN from journal; waves 1..15 rescan list ----
        if (wave == 0) {
            ull bst = ~0ull;
            #pragma unroll
            for (int t = 0; t < 16; ++t) {
                int s = lane + 64 * t;
                if (((aw[s >> 5] >> (s & 31)) & 1u) && s != i) {
                    ull key = ((ull)f2sort(Jl[(m & 15) * TN + s]) << 32) | (uint32_t)s;
                    if (key < bst) bst = key;
                }
            }
            bst = wave_min_ull(bst);
            if (lane == 0) rowkey[i] = bst;
        } else {
            for (int z = wave - 1; z < ncr; z += 15) {
                int r = list_l[z];
                int tsr = ts_l[r];
                const float* Rr = Db + (size_t)r * TN;
                ull bst = ~0ull;
                #pragma unroll
                for (int q = 0; q < 4; ++q) {
                    int s0 = (lane << 2) + (q << 8);
                    float4 v = *(const float4*)(Rr + s0);
                    int4 ts4 = *(const int4*)(&ts_l[s0]);
                    uint32_t bits = (aw[s0 >> 5] >> (s0 & 31)) & 0xFu;
                    #pragma unroll
                    for (int e = 0; e < 4; ++e) {
                        int s = s0 + e;
                        if (!((bits >> e) & 1u) || s == r) continue;
                        int tss = (&ts4.x)[e];
                        float val = (&v.x)[e];
                        int tm = (tss > tsr) ? tss : tsr;
                        if (tm > m16)
                            val = (tss > tsr) ? Jl[(tss & 15) * TN + r]
                                              : Jl[(tsr & 15) * TN + s];
                        ull key = ((ull)f2sort(val) << 32) | (uint32_t)s;
                        if (key < bst) bst = key;
                    }
                }
                bst = wave_min_ull(bst);
                if (lane == 0) rowkey[r] = bst;
            }
        }

        // ---- bar4: light barrier normally; every 8th iter full fence + fix-up ----
        if ((m & 7) == 7) {
            FBAR();   // all window stores landed (order between them unknown)
            // repair same-window store-store races at (i_t1, i_t2): the later
            // merge's journal holds the correct value. Dedupe repeated targets.
            if (k < 64) {
                int t1 = k >> 3, t2 = k & 7;
                if (t1 != t2) {
                    int a = wtarg[t1], c = wtarg[t2];
                    if (a != c) {
                        bool lastA = true, lastC = true;
                        #pragma unroll
                        for (int t = 0; t < 8; ++t) {
                            if (t > t1 && wtarg[t] == a) lastA = false;
                            if (t > t2 && wtarg[t] == c) lastC = false;
                        }
                        if (lastA && lastC) {
                            int later = (t1 > t2) ? t1 : t2;
                            int earlier_i = (t1 > t2) ? c : a;
                            int iterlater = (m & ~7) + later;
                            float v = Jl[(iterlater & 15) * TN + earlier_i];
                            Db[(size_t)a * TN + c] = v;
                        }
                    }
                }
            }
            FBAR();   // fix-ups landed before next window's writes
        } else {
            LBAR();                                        // bar4
        }
    }

    // ---- epilogue: labels = rank of cluster root among active reps ----
    __syncthreads();
    int a = (aw[k >> 5] >> (k & 31)) & 1;
    ull mask = __ballot(a);
    int lanepre = __popcll(mask & (((ull)1 << lane) - 1ull));
    if (lane == 0) prefix_w[wave] = __popcll(mask);
    __syncthreads();
    if (k == 0) {
        int run = 0;
        for (int w2 = 0; w2 < 16; ++w2) { woff[w2] = run; run += prefix_w[w2]; }
    }
    __syncthreads();
    list_l[k] = woff[wave] + lanepre;   // rank of k among active (valid when k active)
    __syncthreads();
    int p = k;
    while (!((aw[p >> 5] >> (p & 31)) & 1u)) p = parent_l[p];
    out_labels[(size_t)b * TN + k] = (float)list_l[p];
}

extern "C" void kernel_launch(void* const* d_in, const int* in_sizes, int n_in,
                              void* d_out, int out_size, void* d_ws, size_t ws_size,
                              hipStream_t stream) {
    const float* x = (const float*)d_in[0];
    float* out = (float*)d_out;

    float* xn    = (float*)d_ws;                          // NB*TN*CD floats
    float* Dwork = xn + (size_t)NB * TN * CD;             // NB*TN*TN floats
    ull*   rowkey = (ull*)(Dwork + (size_t)NB * TN * TN); // NB*TN u64

    float* dist_out   = out;
    float* labels_out = out + (size_t)NB * TN * TN;

    norm_kernel<<<NB * TN, 256, 0, stream>>>(x, xn);
    dim3 g2(16, 16, NB);
    dist_kernel<<<g2, 256, 0, stream>>>(xn, dist_out, Dwork);
    rowmin_init_kernel<<<NB * TN, 256, 0, stream>>>(Dwork, rowkey);
    cluster_kernel<<<NB, 1024, 0, stream>>>(Dwork, rowkey, labels_out);
}

// Round 6
// 3302.483 us; speedup vs baseline: 6.0620x; 1.3345x over previous
//
#include <hip/hip_runtime.h>
#include <stdint.h>

#define TN 1024
#define CD 192
#define NB 8
#define NCLUST 196
#define NMERGE (TN - NCLUST)

typedef unsigned long long ull;

// Workgroup barrier WITHOUT global-memory drain (LDS made visible only).
#define LBAR() asm volatile("s_waitcnt lgkmcnt(0)\n\ts_barrier" ::: "memory")
// Full fence barrier: drains global stores too.
#define FBAR() asm volatile("s_waitcnt vmcnt(0) lgkmcnt(0)\n\ts_barrier" ::: "memory")

__device__ __forceinline__ uint32_t f2sort(float f) {
    uint32_t u = __float_as_uint(f);
    return u ^ ((u >> 31) ? 0xFFFFFFFFu : 0x80000000u);
}

// ---------- DPP min-reductions (VALU latency, no DS-pipe chains) ----------
template<int CTRL>
__device__ __forceinline__ uint32_t dpp_min32(uint32_t x) {
    uint32_t t = (uint32_t)__builtin_amdgcn_update_dpp((int)x, (int)x, CTRL, 0xF, 0xF, false);
    return (t < x) ? t : x;
}
template<int CTRL>
__device__ __forceinline__ ull dpp_min64(ull x) {
    int lo = (int)(uint32_t)x, hi = (int)(uint32_t)(x >> 32);
    int tlo = __builtin_amdgcn_update_dpp(lo, lo, CTRL, 0xF, 0xF, false);
    int thi = __builtin_amdgcn_update_dpp(hi, hi, CTRL, 0xF, 0xF, false);
    ull t = ((ull)(uint32_t)thi << 32) | (uint32_t)tlo;
    return (t < x) ? t : x;
}
// min over all 64 lanes, broadcast to all (readlane -> SGPR)
__device__ __forceinline__ uint32_t wmin32_all(uint32_t x) {
    x = dpp_min32<0x111>(x); x = dpp_min32<0x112>(x);
    x = dpp_min32<0x114>(x); x = dpp_min32<0x118>(x);
    x = dpp_min32<0x142>(x); x = dpp_min32<0x143>(x);
    return (uint32_t)__builtin_amdgcn_readlane((int)x, 63);
}
__device__ __forceinline__ ull wmin64_all(ull x) {
    x = dpp_min64<0x111>(x); x = dpp_min64<0x112>(x);
    x = dpp_min64<0x114>(x); x = dpp_min64<0x118>(x);
    x = dpp_min64<0x142>(x); x = dpp_min64<0x143>(x);
    int lo = __builtin_amdgcn_readlane((int)(uint32_t)x, 63);
    int hi = __builtin_amdgcn_readlane((int)(uint32_t)(x >> 32), 63);
    return ((ull)(uint32_t)hi << 32) | (uint32_t)lo;
}
// min over lanes 0..15 (others must hold ~0), broadcast
__device__ __forceinline__ ull wmin64_16(ull x) {
    x = dpp_min64<0x111>(x); x = dpp_min64<0x112>(x);
    x = dpp_min64<0x114>(x); x = dpp_min64<0x118>(x);
    int lo = __builtin_amdgcn_readlane((int)(uint32_t)x, 15);
    int hi = __builtin_amdgcn_readlane((int)(uint32_t)(x >> 32), 15);
    return ((ull)(uint32_t)hi << 32) | (uint32_t)lo;
}

__device__ __forceinline__ ull shfl_min_ull(ull v) {   // init kernels only
    #pragma unroll
    for (int off = 32; off > 0; off >>= 1) {
        ull o = (ull)__shfl_xor((long long)v, off, 64);
        if (o < v) v = o;
    }
    return v;
}

// ---------------- normalize rows: xn = x / ||x|| ----------------
__global__ void norm_kernel(const float* __restrict__ x, float* __restrict__ xn) {
    int row = blockIdx.x;
    int t = threadIdx.x;
    __shared__ float ssum[4];
    float v = 0.f;
    if (t < CD) v = x[(size_t)row * CD + t];
    float s = v * v;
    #pragma unroll
    for (int off = 32; off > 0; off >>= 1) s += __shfl_xor(s, off, 64);
    if ((t & 63) == 0) ssum[t >> 6] = s;
    __syncthreads();
    float tot = ssum[0] + ssum[1] + ssum[2] + ssum[3];
    float nrm = __fsqrt_rn(tot);
    if (t < CD) xn[(size_t)row * CD + t] = __fdiv_rn(v, nrm);
}

// ---------------- dist = 1 - xn @ xn^T, 64x64 tiles ----------------
#define KC 32
__global__ __launch_bounds__(256) void dist_kernel(const float* __restrict__ xn,
                                                   float* __restrict__ dout,
                                                   float* __restrict__ dwork) {
    int b = blockIdx.z;
    int bm = blockIdx.y, bn = blockIdx.x;
    const float* X = xn + (size_t)b * TN * CD;
    __shared__ float As[KC][68];
    __shared__ float Bs[KC][68];
    int tid = threadIdx.x;
    int tx = tid & 15, ty = tid >> 4;
    int lr = tid >> 2;
    int lq = tid & 3;
    float acc[4][4];
    #pragma unroll
    for (int r = 0; r < 4; ++r)
        #pragma unroll
        for (int c = 0; c < 4; ++c) acc[r][c] = 0.f;

    for (int kc = 0; kc < CD; kc += KC) {
        float4 a0 = *(const float4*)&X[(size_t)(bm * 64 + lr) * CD + kc + lq * 4];
        float4 a1 = *(const float4*)&X[(size_t)(bm * 64 + lr) * CD + kc + (lq + 4) * 4];
        float4 b0 = *(const float4*)&X[(size_t)(bn * 64 + lr) * CD + kc + lq * 4];
        float4 b1 = *(const float4*)&X[(size_t)(bn * 64 + lr) * CD + kc + (lq + 4) * 4];
        __syncthreads();
        As[lq * 4 + 0][lr] = a0.x; As[lq * 4 + 1][lr] = a0.y;
        As[lq * 4 + 2][lr] = a0.z; As[lq * 4 + 3][lr] = a0.w;
        As[lq * 4 + 16][lr] = a1.x; As[lq * 4 + 17][lr] = a1.y;
        As[lq * 4 + 18][lr] = a1.z; As[lq * 4 + 19][lr] = a1.w;
        Bs[lq * 4 + 0][lr] = b0.x; Bs[lq * 4 + 1][lr] = b0.y;
        Bs[lq * 4 + 2][lr] = b0.z; Bs[lq * 4 + 3][lr] = b0.w;
        Bs[lq * 4 + 16][lr] = b1.x; Bs[lq * 4 + 17][lr] = b1.y;
        Bs[lq * 4 + 18][lr] = b1.z; Bs[lq * 4 + 19][lr] = b1.w;
        __syncthreads();
        #pragma unroll
        for (int kk = 0; kk < KC; ++kk) {
            float4 av = *(const float4*)&As[kk][ty * 4];
            float4 bv = *(const float4*)&Bs[kk][tx * 4];
            acc[0][0] += av.x * bv.x; acc[0][1] += av.x * bv.y;
            acc[0][2] += av.x * bv.z; acc[0][3] += av.x * bv.w;
            acc[1][0] += av.y * bv.x; acc[1][1] += av.y * bv.y;
            acc[1][2] += av.y * bv.z; acc[1][3] += av.y * bv.w;
            acc[2][0] += av.z * bv.x; acc[2][1] += av.z * bv.y;
            acc[2][2] += av.z * bv.z; acc[2][3] += av.z * bv.w;
            acc[3][0] += av.w * bv.x; acc[3][1] += av.w * bv.y;
            acc[3][2] += av.w * bv.z; acc[3][3] += av.w * bv.w;
        }
    }
    size_t obase = (size_t)b * TN * TN;
    #pragma unroll
    for (int r = 0; r < 4; ++r) {
        int mrow = bm * 64 + ty * 4 + r;
        float4 o;
        o.x = 1.0f - acc[r][0]; o.y = 1.0f - acc[r][1];
        o.z = 1.0f - acc[r][2]; o.w = 1.0f - acc[r][3];
        size_t idx = obase + (size_t)mrow * TN + bn * 64 + tx * 4;
        *(float4*)&dout[idx] = o;
        *(float4*)&dwork[idx] = o;
    }
}

// ---------------- per-row top-2 init (two passes) ----------------
__global__ void rowmin_init_kernel(const float* __restrict__ D,
                                   ull* __restrict__ rowkey, ull* __restrict__ rowkey2) {
    int gid = blockIdx.x;
    int bb = gid >> 10, r = gid & 1023;
    const float* Drow = D + (size_t)bb * TN * TN + (size_t)r * TN;
    int t = threadIdx.x;
    __shared__ ull part[4];
    __shared__ ull m1s;
    // pass 1: min1
    ull k = ~0ull;
    for (int s = t; s < TN; s += 256) {
        if (s != r) {
            ull key = ((ull)f2sort(Drow[s]) << 32) | (uint32_t)s;
            if (key < k) k = key;
        }
    }
    k = shfl_min_ull(k);
    if ((t & 63) == 0) part[t >> 6] = k;
    __syncthreads();
    if (t == 0) {
        ull m = part[0];
        #pragma unroll
        for (int w = 1; w < 4; ++w) if (part[w] < m) m = part[w];
        rowkey[gid] = m;
        m1s = m;
    }
    __syncthreads();
    ull m1 = m1s;
    int c1 = (int)(uint32_t)m1;
    // pass 2: min2 (exclude col c1)
    ull k2 = ~0ull;
    for (int s = t; s < TN; s += 256) {
        if (s != r && s != c1) {
            ull key = ((ull)f2sort(Drow[s]) << 32) | (uint32_t)s;
            if (key < k2) k2 = key;
        }
    }
    k2 = shfl_min_ull(k2);
    __syncthreads();
    if ((t & 63) == 0) part[t >> 6] = k2;
    __syncthreads();
    if (t == 0) {
        ull m = part[0];
        #pragma unroll
        for (int w = 1; w < 4; ++w) if (part[w] < m) m = part[w];
        rowkey2[gid] = m;
    }
}

// ---------------- agglomerative clustering: 16 waves/batch ----------------
// R5 structure (journal bridge + light barriers + fence/fixup) with:
// DPP reductions, uniform-branch journal fast path, top-2 rowkey, fused row-i NN.
__global__ __launch_bounds__(1024) void cluster_kernel(float* __restrict__ D,
                                                       const ull* __restrict__ rk_init,
                                                       const ull* __restrict__ rk2_init,
                                                       float* __restrict__ out_labels) {
    int b = blockIdx.x;
    float* Db = D + (size_t)b * TN * TN;
    int k = threadIdx.x;
    int lane = k & 63, wave = k >> 6;

    __shared__ float Jl[16 * TN];        // 64 KB journal ring of last 16 merged rows
    __shared__ ull rowkey[TN];           // min1: (sortable val << 32) | col; ~0 = dead
    __shared__ ull rowkey2[TN];          // min2 or ~0 = unknown
    __shared__ float sizes_l[TN];
    __shared__ int ts_l[TN] __attribute__((aligned(16)));
    __shared__ int parent_l[TN];
    __shared__ uint32_t aw[TN / 32];
    __shared__ int list_l[TN];
    __shared__ int nrecb[2];
    __shared__ ull wpA[16], wpB1[16], wpB2[16];
    __shared__ int bc_i, bc_j, bc_tsi, bc_tsj;
    __shared__ float bc_ni, bc_nj;
    __shared__ int wtarg[8];
    __shared__ int prefix_w[16], woff[16];

    rowkey[k] = rk_init[b * TN + k];
    rowkey2[k] = rk2_init[b * TN + k];
    sizes_l[k] = 1.0f;
    ts_l[k] = -1000000;
    parent_l[k] = k;
    if (k < TN / 32) aw[k] = 0xFFFFFFFFu;
    if (k < 2) nrecb[k] = 0;
    __syncthreads();

    for (int m = 0; m < NMERGE; ++m) {
        int m16 = m - 16;

        // ---- Phase A: global argmin (val, row) via DPP + ballot ----
        ull K0 = rowkey[k];
        uint32_t v32 = (uint32_t)(K0 >> 32);
        uint32_t vm = wmin32_all(v32);
        ull bmA = __ballot(v32 == vm);
        int lm = __ffsll((long long)bmA) - 1;
        if (lane == 0) wpA[wave] = ((ull)vm << 32) | (uint32_t)(wave * 64 + lm);
        LBAR();                                            // bar1
        if (wave == 0) {
            ull t = (lane < 16) ? wpA[lane] : ~0ull;
            ull g = wmin64_16(t);
            if (lane == 0) {
                int i = (int)(uint32_t)g;
                int j = (int)(uint32_t)rowkey[i];
                bc_i = i; bc_j = j;
                bc_tsi = ts_l[i]; bc_tsj = ts_l[j];
                float ni = sizes_l[i], nj = sizes_l[j];
                bc_ni = ni; bc_nj = nj;
                sizes_l[i] = __fadd_rn(ni, nj);
                ts_l[i] = m;
                rowkey[j] = ~0ull;
                rowkey2[j] = ~0ull;
                parent_l[j] = i;
                aw[j >> 5] &= ~(1u << (j & 31));
                wtarg[m & 7] = i;
                nrecb[(m & 1) ^ 1] = 0;
            }
        }
        LBAR();                                            // bar2
        int i = bc_i, j = bc_j;
        int tsi = bc_tsi, tsj = bc_tsj;
        float ni = bc_ni, nj = bc_nj;
        float ssum = __fadd_rn(ni, nj);

        // ---- Phase B: fresh rows i,j; uniform branch skips global load when
        //      the whole row lives in the LDS journal ----
        int tsk = ts_l[k];
        float di, dj;
        if (tsi > m16) {
            di = (tsk > tsi) ? Jl[(tsk & 15) * TN + i] : Jl[(tsi & 15) * TN + k];
        } else {
            di = (tsk > m16) ? Jl[(tsk & 15) * TN + i] : Db[(size_t)i * TN + k];
        }
        if (tsj > m16) {
            dj = (tsk > tsj) ? Jl[(tsk & 15) * TN + j] : Jl[(tsj & 15) * TN + k];
        } else {
            dj = (tsk > m16) ? Jl[(tsk & 15) * TN + j] : Db[(size_t)j * TN + k];
        }
        float nr = __fdiv_rn(__fadd_rn(__fmul_rn(ni, di), __fmul_rn(nj, dj)), ssum);
        Jl[(m & 15) * TN + k] = nr;                        // journal (LDS)
        Db[(size_t)i * TN + k] = nr;                       // coalesced row write
        if (K0 != ~0ull) Db[(size_t)k * TN + i] = nr;      // scattered col write (live only)

        // ---- fused row-i NN: per-wave top-2 of nr (2 ballot-DPP passes) ----
        uint32_t cv = (K0 != ~0ull && k != i && k != j) ? f2sort(nr) : 0xFFFFFFFFu;
        uint32_t w1 = wmin32_all(cv);
        ull b1m = __ballot(cv == w1);
        int l1 = __ffsll((long long)b1m) - 1;
        uint32_t cv2 = (lane == l1) ? 0xFFFFFFFFu : cv;
        uint32_t w2 = wmin32_all(cv2);
        ull b2m = __ballot(cv2 == w2);
        int l2 = __ffsll((long long)b2m) - 1;
        if (lane == 0) {
            wpB1[wave] = ((ull)w1 << 32) | (uint32_t)(wave * 64 + l1);
            wpB2[wave] = ((ull)w2 << 32) | (uint32_t)(wave * 64 + l2);
        }

        // ---- Phase D: top-2 incremental maintenance ----
        if (K0 != ~0ull && k != i && k != j) {
            ull M0 = rowkey2[k];
            uint32_t c1 = (uint32_t)K0;
            ull nk = ((ull)f2sort(nr) << 32) | (uint32_t)i;
            bool k1 = (c1 == (uint32_t)i) || (c1 == (uint32_t)j);
            bool mvalid = (M0 != ~0ull);
            if (mvalid) {
                uint32_t c2 = (uint32_t)M0;
                if (c2 == (uint32_t)i || c2 == (uint32_t)j) mvalid = false;
            }
            if (!k1) {
                if (nk < K0) { rowkey[k] = nk; rowkey2[k] = K0; }
                else rowkey2[k] = mvalid ? ((nk < M0) ? nk : M0) : ~0ull;
            } else {
                if (mvalid) {
                    if (nk < M0) { rowkey[k] = nk; rowkey2[k] = M0; }
                    else { rowkey[k] = M0; rowkey2[k] = ~0ull; }
                } else {
                    int idx = atomicAdd(&nrecb[m & 1], 1); list_l[idx] = k;
                }
            }
        }
        LBAR();                                            // bar3
        int ncr = nrecb[m & 1];

        // ---- Phase C: wave0 finalizes row i's top-2; waves 1..15 rescan list ----
        if (wave == 0) {
            ull a = (lane < 16) ? wpB1[lane] : ~0ull;
            ull bb = (lane < 16) ? wpB2[lane] : ~0ull;
            ull m1 = wmin64_16(a);
            ull bm = __ballot((a == m1) && (lane < 16));
            int lw = __ffsll((long long)bm) - 1;
            ull a2 = (lane == lw) ? bb : a;
            ull m2 = wmin64_16(a2);
            if (lane == 0) { rowkey[i] = m1; rowkey2[i] = m2; }
        } else {
            for (int z = wave - 1; z < ncr; z += 15) {
                int r = list_l[z];
                int tsr = ts_l[r];
                const float* Rr = Db + (size_t)r * TN;
                ull a = ~0ull, bsec = ~0ull;
                #pragma unroll
                for (int q = 0; q < 4; ++q) {
                    int s0 = (lane << 2) + (q << 8);
                    float4 v = *(const float4*)(Rr + s0);
                    int4 ts4 = *(const int4*)(&ts_l[s0]);
                    uint32_t bits = (aw[s0 >> 5] >> (s0 & 31)) & 0xFu;
                    #pragma unroll
                    for (int e = 0; e < 4; ++e) {
                        int s = s0 + e;
                        if (!((bits >> e) & 1u) || s == r) continue;
                        int tss = (&ts4.x)[e];
                        float val = (&v.x)[e];
                        int tm = (tss > tsr) ? tss : tsr;
                        if (tm > m16)
                            val = (tss > tsr) ? Jl[(tss & 15) * TN + r]
                                              : Jl[(tsr & 15) * TN + s];
                        ull key = ((ull)f2sort(val) << 32) | (uint32_t)s;
                        if (key < a) { bsec = a; a = key; }
                        else if (key < bsec) { bsec = key; }
                    }
                }
                ull m1 = wmin64_all(a);
                ull bm = __ballot(a == m1);
                int lw = __ffsll((long long)bm) - 1;
                ull a2 = (lane == lw) ? bsec : a;
                ull m2 = wmin64_all(a2);
                if (lane == 0) { rowkey[r] = m1; rowkey2[r] = m2; }
            }
        }

        // ---- bar4: light barrier; every 8th iter full fence + race fix-up ----
        if ((m & 7) == 7) {
            FBAR();
            if (k < 64) {
                int t1 = k >> 3, t2 = k & 7;
                if (t1 != t2) {
                    int a = wtarg[t1], c = wtarg[t2];
                    if (a != c) {
                        bool lastA = true, lastC = true;
                        #pragma unroll
                        for (int t = 0; t < 8; ++t) {
                            if (t > t1 && wtarg[t] == a) lastA = false;
                            if (t > t2 && wtarg[t] == c) lastC = false;
                        }
                        if (lastA && lastC) {
                            int later = (t1 > t2) ? t1 : t2;
                            int earlier_i = (t1 > t2) ? c : a;
                            int iterlater = (m & ~7) + later;
                            float v = Jl[(iterlater & 15) * TN + earlier_i];
                            Db[(size_t)a * TN + c] = v;
                        }
                    }
                }
            }
            FBAR();
        } else {
            LBAR();                                        // bar4
        }
    }

    // ---- epilogue: labels = rank of cluster root among active reps ----
    __syncthreads();
    int a = (aw[k >> 5] >> (k & 31)) & 1;
    ull mask = __ballot(a);
    int lanepre = __popcll(mask & (((ull)1 << lane) - 1ull));
    if (lane == 0) prefix_w[wave] = __popcll(mask);
    __syncthreads();
    if (k == 0) {
        int run = 0;
        for (int w2 = 0; w2 < 16; ++w2) { woff[w2] = run; run += prefix_w[w2]; }
    }
    __syncthreads();
    list_l[k] = woff[wave] + lanepre;
    __syncthreads();
    int p = k;
    while (!((aw[p >> 5] >> (p & 31)) & 1u)) p = parent_l[p];
    out_labels[(size_t)b * TN + k] = (float)list_l[p];
}

extern "C" void kernel_launch(void* const* d_in, const int* in_sizes, int n_in,
                              void* d_out, int out_size, void* d_ws, size_t ws_size,
                              hipStream_t stream) {
    const float* x = (const float*)d_in[0];
    float* out = (float*)d_out;

    float* xn     = (float*)d_ws;                           // NB*TN*CD floats
    float* Dwork  = xn + (size_t)NB * TN * CD;              // NB*TN*TN floats
    ull*   rowkey = (ull*)(Dwork + (size_t)NB * TN * TN);   // NB*TN u64
    ull*   rowkey2 = rowkey + (size_t)NB * TN;              // NB*TN u64

    float* dist_out   = out;
    float* labels_out = out + (size_t)NB * TN * TN;

    norm_kernel<<<NB * TN, 256, 0, stream>>>(x, xn);
    dim3 g2(16, 16, NB);
    dist_kernel<<<g2, 256, 0, stream>>>(xn, dist_out, Dwork);
    rowmin_init_kernel<<<NB * TN, 256, 0, stream>>>(Dwork, rowkey, rowkey2);
    cluster_kernel<<<NB, 1024, 0, stream>>>(Dwork, rowkey, rowkey2, labels_out);
}